// Round 3
// baseline (1310.556 us; speedup 1.0000x reference)
//
#include <hip/hip_runtime.h>

#define DN 128
#define DE 64
#define DEMB 128
#define DHID 256
#define DCAT 576   // [q:128 | k:128 | v:128 | hr:128 | wqe:64]
#define KOFF 128
#define VOFF 256
#define ROFF 384
#define EOFF 512
#define SCALE 0.08838834764831845f  // 1/sqrt(128)

// ---------- fused weight prep: Wcat[256][576] = [Wq*s | Wk | Wv | Wr | (Wq@We^T)*s] ----------
__global__ void k_prep_w(const float* __restrict__ Wq, const float* __restrict__ Wk,
                         const float* __restrict__ Wv, const float* __restrict__ Wr,
                         const float* __restrict__ We, float* __restrict__ Wcat) {
  int idx = blockIdx.x * 256 + threadIdx.x;
  if (idx >= DHID * DCAT) return;
  int kk = idx / DCAT, j = idx % DCAT;
  float v;
  if (j < 128)       v = Wq[kk*DEMB + j] * SCALE;
  else if (j < 256)  v = Wk[kk*DEMB + (j-128)];
  else if (j < 384)  v = Wv[kk*DEMB + (j-256)];
  else if (j < 512)  v = Wr[kk*DEMB + (j-384)];
  else {
    int c = j - 512;
    float a = 0.f;
    for (int t = 0; t < DEMB; ++t) a += Wq[kk*DEMB + t] * We[c*DEMB + t];
    v = a * SCALE;
  }
  Wcat[idx] = v;
}

// bcat[576]; be folded into k- and v-bias so e's bias is handled exactly
__global__ void k_prep_b(const float* __restrict__ bq, const float* __restrict__ bk,
                         const float* __restrict__ bv, const float* __restrict__ br,
                         const float* __restrict__ be, const float* __restrict__ We,
                         float* __restrict__ bcat) {
  int j = blockIdx.x * 256 + threadIdx.x;
  if (j >= DCAT) return;
  float v;
  if (j < 128)       v = bq[j] * SCALE;
  else if (j < 256)  v = bk[j-128] + be[j-128];
  else if (j < 384)  v = bv[j-256] + be[j-256];
  else if (j < 512)  v = br[j-384];
  else {
    int c = j - 512;
    float a = 0.f;
    for (int t = 0; t < DEMB; ++t) a += bq[t] * We[c*DEMB + t];
    v = a * SCALE;
  }
  bcat[j] = v;
}

// ---------- CSR build ----------
__global__ void k_deg(const int* __restrict__ ei, int* __restrict__ degi, int nE) {
  int e = blockIdx.x * 256 + threadIdx.x;
  if (e < nE) atomicAdd(&degi[ei[nE + e]], 1);
}

__global__ void k_dinv(const int* __restrict__ degi, float* __restrict__ dinv, int nN) {
  int n = blockIdx.x * 256 + threadIdx.x;
  if (n < nN) dinv[n] = rsqrtf(1.0f + (float)degi[n]);
}

// single-block exclusive scan over degi -> row_ptr (n up to ~50k: 49 tiles of 1024)
__global__ __launch_bounds__(1024) void k_scan(const int* __restrict__ degi,
                                               int* __restrict__ row_ptr, int n) {
  __shared__ int sm[1024];
  __shared__ int carry;
  if (threadIdx.x == 0) carry = 0;
  __syncthreads();
  for (int base = 0; base < n; base += 1024) {
    int i = base + threadIdx.x;
    int v = (i < n) ? degi[i] : 0;
    sm[threadIdx.x] = v;
    __syncthreads();
    int val = v;
    for (int off = 1; off < 1024; off <<= 1) {
      int t = (threadIdx.x >= off) ? sm[threadIdx.x - off] : 0;
      __syncthreads();
      val += t;
      sm[threadIdx.x] = val;
      __syncthreads();
    }
    int c0 = carry;
    if (i < n) row_ptr[i] = c0 + val - v;   // exclusive
    int total = sm[1023];
    __syncthreads();
    if (threadIdx.x == 0) carry = c0 + total;
    __syncthreads();
  }
  if (threadIdx.x == 0) row_ptr[n] = carry;
}

__global__ void k_scatter(const int* __restrict__ ei, const int* __restrict__ row_ptr,
                          int* __restrict__ cursor, int* __restrict__ csr_src,
                          int* __restrict__ csr_eid, int nE) {
  int e = blockIdx.x * 256 + threadIdx.x;
  if (e >= nE) return;
  int dst = ei[nE + e];
  int pos = row_ptr[dst] + atomicAdd(&cursor[dst], 1);
  csr_src[pos] = ei[e];
  csr_eid[pos] = e;
}

// ---------- generic f32 GEMM: C[M,Ncols] = A[M,K] @ B[K,Ncols] (+bias) ----------
// BM=128 BN=64 BK=16, 256 threads, 8x4 per thread
__global__ __launch_bounds__(256) void k_gemm(const float* __restrict__ A,
                                              const float* __restrict__ B,
                                              const float* __restrict__ bias,
                                              float* __restrict__ C,
                                              int M, int Ncols, int K) {
  __shared__ float As[16][128];
  __shared__ float Bs[16][64];
  int tid = threadIdx.x;
  int tx = tid & 15, ty = tid >> 4;
  int bm0 = blockIdx.x * 128;
  int bn0 = blockIdx.y * 64;
  float acc[8][4] = {};
  for (int k0 = 0; k0 < K; k0 += 16) {
    #pragma unroll
    for (int j = 0; j < 2; ++j) {                 // A tile: 2048 f32
      int idx = tid + j * 256;
      int row = idx >> 2, kg = idx & 3;
      int grow = bm0 + row;
      float4 a4 = make_float4(0.f, 0.f, 0.f, 0.f);
      if (grow < M) a4 = *reinterpret_cast<const float4*>(&A[(size_t)grow * K + k0 + kg * 4]);
      As[kg*4+0][row] = a4.x; As[kg*4+1][row] = a4.y;
      As[kg*4+2][row] = a4.z; As[kg*4+3][row] = a4.w;
    }
    {                                              // B tile: 1024 f32
      int row = tid >> 4, cg = tid & 15;
      float4 b4 = *reinterpret_cast<const float4*>(&B[(size_t)(k0 + row) * Ncols + bn0 + cg * 4]);
      *reinterpret_cast<float4*>(&Bs[row][cg * 4]) = b4;
    }
    __syncthreads();
    #pragma unroll
    for (int kk = 0; kk < 16; ++kk) {
      float a[8], b[4];
      #pragma unroll
      for (int r = 0; r < 8; ++r) a[r] = As[kk][ty * 8 + r];
      #pragma unroll
      for (int c = 0; c < 4; ++c) b[c] = Bs[kk][tx * 4 + c];
      #pragma unroll
      for (int r = 0; r < 8; ++r)
        #pragma unroll
        for (int c = 0; c < 4; ++c) acc[r][c] += a[r] * b[c];
    }
    __syncthreads();
  }
  #pragma unroll
  for (int r = 0; r < 8; ++r) {
    int grow = bm0 + ty * 8 + r;
    if (grow >= M) continue;
    int gcol = bn0 + tx * 4;
    float4 o;
    o.x = acc[r][0] + (bias ? bias[gcol + 0] : 0.f);
    o.y = acc[r][1] + (bias ? bias[gcol + 1] : 0.f);
    o.z = acc[r][2] + (bias ? bias[gcol + 2] : 0.f);
    o.w = acc[r][3] + (bias ? bias[gcol + 3] : 0.f);
    *reinterpret_cast<float4*>(&C[(size_t)grow * Ncols + gcol]) = o;
  }
}

// ---------- GCN aggregate: one wave per node, h = relu(dinv[n]*sum + xw[n]*dinv^2 + b1) ----------
__global__ __launch_bounds__(256) void k_gcn(const float* __restrict__ xw,
                                             const int* __restrict__ row_ptr,
                                             const int* __restrict__ csr_src,
                                             const float* __restrict__ dinv,
                                             const float* __restrict__ b1,
                                             float* __restrict__ h, int nN) {
  int wave = threadIdx.x >> 6, lane = threadIdx.x & 63;
  int n = blockIdx.x * 4 + wave;
  if (n >= nN) return;
  int beg = row_ptr[n], end = row_ptr[n + 1];
  float4 acc = make_float4(0.f, 0.f, 0.f, 0.f);
  for (int i = beg; i < end; ++i) {
    int src = csr_src[i];
    float ds = dinv[src];
    float4 xv = *reinterpret_cast<const float4*>(&xw[(size_t)src * DHID + lane * 4]);
    acc.x += ds * xv.x; acc.y += ds * xv.y; acc.z += ds * xv.z; acc.w += ds * xv.w;
  }
  float dn = dinv[n];
  float self = dn * dn;
  float4 xs = *reinterpret_cast<const float4*>(&xw[(size_t)n * DHID + lane * 4]);
  float4 bb = *reinterpret_cast<const float4*>(&b1[lane * 4]);
  float4 o;
  o.x = fmaxf(acc.x * dn + xs.x * self + bb.x, 0.f);
  o.y = fmaxf(acc.y * dn + xs.y * self + bb.y, 0.f);
  o.z = fmaxf(acc.z * dn + xs.z * self + bb.z, 0.f);
  o.w = fmaxf(acc.w * dn + xs.w * self + bb.w, 0.f);
  *reinterpret_cast<float4*>(&h[(size_t)n * DHID + lane * 4]) = o;
}

// ---------- fused attention + root + LayerNorm + pool: one wave per dst node ----------
__global__ __launch_bounds__(256) void k_attn(const float* __restrict__ qkvr,
                                              const float* __restrict__ edge_attr,
                                              const float* __restrict__ We,
                                              const int* __restrict__ row_ptr,
                                              const int* __restrict__ csr_src,
                                              const int* __restrict__ csr_eid,
                                              const int* __restrict__ batch,
                                              const float* __restrict__ gamma,
                                              const float* __restrict__ beta,
                                              float* __restrict__ pool,
                                              float* __restrict__ cnt, int nN) {
  int wave = threadIdx.x >> 6, lane = threadIdx.x & 63;
  int n = blockIdx.x * 4 + wave;
  if (n >= nN) return;
  const float* base = &qkvr[(size_t)n * DCAT];
  float2 q2 = *reinterpret_cast<const float2*>(&base[lane * 2]);        // pre-scaled by 1/sqrt(128)
  float wqe = base[EOFF + lane];                                        // (We@q)*s, lane-th of 64
  float m = -1e30f, s = 0.f;
  float2 vacc = make_float2(0.f, 0.f);
  float eacc = 0.f;
  int beg = row_ptr[n], end = row_ptr[n + 1];
  for (int i = beg; i < end; ++i) {
    int src = csr_src[i];
    int eid = csr_eid[i];
    float ea = edge_attr[(size_t)eid * DE + lane];
    const float* sb = &qkvr[(size_t)src * DCAT];
    float2 k2 = *reinterpret_cast<const float2*>(&sb[KOFF + lane * 2]);
    float part = ea * wqe + k2.x * q2.x + k2.y * q2.y;
    #pragma unroll
    for (int off = 1; off < 64; off <<= 1) part += __shfl_xor(part, off);
    float logit = part;                                                 // all lanes hold it
    float mn = fmaxf(m, logit);
    float cs = __expf(m - mn);                                          // 0 on first edge
    float p  = __expf(logit - mn);
    s = s * cs + p;
    float2 v2 = *reinterpret_cast<const float2*>(&sb[VOFF + lane * 2]);
    vacc.x = vacc.x * cs + p * v2.x;
    vacc.y = vacc.y * cs + p * v2.y;
    eacc = eacc * cs + p * ea;
    m = mn;
  }
  float2 o2 = make_float2(0.f, 0.f);
  if (s > 0.f) {
    float inv = 1.f / s;
    vacc.x *= inv; vacc.y *= inv; eacc *= inv;
    o2 = vacc;
    // out += (sum alpha*edge_attr) @ We  — per-node 64x128 matvec
    for (int c = 0; c < 64; ++c) {
      float ec = __shfl(eacc, c);
      float2 w2 = *reinterpret_cast<const float2*>(&We[c * DEMB + lane * 2]);
      o2.x += ec * w2.x; o2.y += ec * w2.y;
    }
  }
  float2 hr2 = *reinterpret_cast<const float2*>(&base[ROFF + lane * 2]);
  o2.x += hr2.x; o2.y += hr2.y;
  // LayerNorm over 128 (biased var) + ReLU
  float s1 = o2.x + o2.y, sq = o2.x * o2.x + o2.y * o2.y;
  #pragma unroll
  for (int off = 1; off < 64; off <<= 1) {
    s1 += __shfl_xor(s1, off);
    sq += __shfl_xor(sq, off);
  }
  float mu = s1 * (1.f / 128.f);
  float var = sq * (1.f / 128.f) - mu * mu;
  float rstd = rsqrtf(var + 1e-5f);
  float2 g2 = *reinterpret_cast<const float2*>(&gamma[lane * 2]);
  float2 b2 = *reinterpret_cast<const float2*>(&beta[lane * 2]);
  float y0 = fmaxf((o2.x - mu) * rstd * g2.x + b2.x, 0.f);
  float y1 = fmaxf((o2.y - mu) * rstd * g2.y + b2.y, 0.f);
  int b = batch[n];
  atomicAdd(&pool[b * DEMB + lane * 2 + 0], y0);
  atomicAdd(&pool[b * DEMB + lane * 2 + 1], y1);
  if (lane == 0) atomicAdd(&cnt[b], 1.f);
}

__global__ void k_final(const float* __restrict__ pool, const float* __restrict__ cnt,
                        float* __restrict__ out, int total) {
  int i = blockIdx.x * 256 + threadIdx.x;
  if (i < total) out[i] = pool[i] / fmaxf(cnt[i >> 7], 1.f);
}

extern "C" void kernel_launch(void* const* d_in, const int* in_sizes, int n_in,
                              void* d_out, int out_size, void* d_ws, size_t ws_size,
                              hipStream_t stream) {
  const float* x         = (const float*)d_in[0];
  const float* edge_attr = (const float*)d_in[1];
  const int*   edge_index= (const int*)d_in[2];
  const int*   batch     = (const int*)d_in[3];
  const float* W1 = (const float*)d_in[4];
  const float* b1 = (const float*)d_in[5];
  const float* Wq = (const float*)d_in[6];  const float* bq = (const float*)d_in[7];
  const float* Wk = (const float*)d_in[8];  const float* bk = (const float*)d_in[9];
  const float* Wv = (const float*)d_in[10]; const float* bv = (const float*)d_in[11];
  const float* We = (const float*)d_in[12]; const float* be = (const float*)d_in[13];
  const float* Wr = (const float*)d_in[14]; const float* br = (const float*)d_in[15];
  const float* gamma = (const float*)d_in[16];
  const float* beta  = (const float*)d_in[17];
  float* out = (float*)d_out;

  const int nN = in_sizes[0] / DN;       // 50000
  const int nE = in_sizes[1] / DE;       // 1600000

  // ---- workspace layout (bump allocator, 256B aligned) ----
  char* p = (char*)d_ws;
  auto alloc = [&](size_t bytes) -> void* {
    void* r = (void*)p;
    p += (bytes + 255) & ~(size_t)255;
    return r;
  };
  // zeroed region first (one memset)
  int*   degi   = (int*)  alloc((size_t)nN * 4);
  int*   cursor = (int*)  alloc((size_t)nN * 4);
  float* pool   = (float*)alloc((size_t)out_size * 4);
  float* cnt    = (float*)alloc(64 * 4);
  size_t zero_bytes = (size_t)(p - (char*)d_ws);
  int*   row_ptr = (int*)  alloc((size_t)(nN + 1) * 4);
  float* dinv    = (float*)alloc((size_t)nN * 4);
  int*   csr_src = (int*)  alloc((size_t)nE * 4);
  int*   csr_eid = (int*)  alloc((size_t)nE * 4);
  float* Wcat    = (float*)alloc((size_t)DHID * DCAT * 4);
  float* bcat    = (float*)alloc((size_t)DCAT * 4);
  float* h       = (float*)alloc((size_t)nN * DHID * 4);
  // xw is dead after k_gcn; alias it with qkvr's region (qkvr is larger)
  float* qkvr    = (float*)alloc((size_t)nN * DCAT * 4);
  float* xw      = qkvr;
  size_t required = (size_t)(p - (char*)d_ws);
  if (ws_size < required) return;  // refuse to scribble past the workspace

  hipMemsetAsync(d_ws, 0, zero_bytes, stream);

  k_prep_w<<<(DHID * DCAT + 255) / 256, 256, 0, stream>>>(Wq, Wk, Wv, Wr, We, Wcat);
  k_prep_b<<<3, 256, 0, stream>>>(bq, bk, bv, br, be, We, bcat);
  k_deg<<<(nE + 255) / 256, 256, 0, stream>>>(edge_index, degi, nE);
  k_dinv<<<(nN + 255) / 256, 256, 0, stream>>>(degi, dinv, nN);
  k_scan<<<1, 1024, 0, stream>>>(degi, row_ptr, nN);
  k_scatter<<<(nE + 255) / 256, 256, 0, stream>>>(edge_index, row_ptr, cursor,
                                                  csr_src, csr_eid, nE);
  // xw = x @ W1   [nN,128]@[128,256]
  {
    dim3 g((nN + 127) / 128, DHID / 64);
    k_gemm<<<g, 256, 0, stream>>>(x, W1, nullptr, xw, nN, DHID, DN);
  }
  k_gcn<<<(nN + 3) / 4, 256, 0, stream>>>(xw, row_ptr, csr_src, dinv, b1, h, nN);
  // qkvr = h @ Wcat + bcat   [nN,256]@[256,576]  (overwrites xw region — xw is dead)
  {
    dim3 g((nN + 127) / 128, DCAT / 64);
    k_gemm<<<g, 256, 0, stream>>>(h, Wcat, bcat, qkvr, nN, DCAT, DHID);
  }
  k_attn<<<(nN + 3) / 4, 256, 0, stream>>>(qkvr, edge_attr, We, row_ptr, csr_src,
                                           csr_eid, batch, gamma, beta, pool, cnt, nN);
  k_final<<<(out_size + 255) / 256, 256, 0, stream>>>(pool, cnt, out, out_size);
}

// Round 4
// 1288.073 us; speedup vs baseline: 1.0175x; 1.0175x over previous
//
#include <hip/hip_runtime.h>

#define DN 128
#define DE 64
#define DEMB 128
#define DHID 256
#define DCAT 576   // [q:128 | kv interleaved:256 | hr:128 | wqe:64]
#define KOFF 128   // kv region: lane l holds (k[2l],k[2l+1],v[2l],v[2l+1]) as float4
#define ROFF 384
#define EOFF 512
#define SCALE 0.08838834764831845f  // 1/sqrt(128)
#define CK 8

// ---------- fused weight prep: Wcat[256][576] = [Wq*s | interleave(Wk,Wv) | Wr | (Wq@We^T)*s] ----------
__global__ void k_prep_w(const float* __restrict__ Wq, const float* __restrict__ Wk,
                         const float* __restrict__ Wv, const float* __restrict__ Wr,
                         const float* __restrict__ We, float* __restrict__ Wcat) {
  int idx = blockIdx.x * 256 + threadIdx.x;
  if (idx >= DHID * DCAT) return;
  int kk = idx / DCAT, j = idx % DCAT;
  float v;
  if (j < 128)       v = Wq[kk*DEMB + j] * SCALE;
  else if (j < 384) {
    int t = j - 128, g = t >> 2, r = t & 3;
    int col = 2*g + (r & 1);
    v = (r < 2) ? Wk[kk*DEMB + col] : Wv[kk*DEMB + col];
  }
  else if (j < 512)  v = Wr[kk*DEMB + (j-384)];
  else {
    int c = j - 512;
    float a = 0.f;
    for (int t = 0; t < DEMB; ++t) a += Wq[kk*DEMB + t] * We[c*DEMB + t];
    v = a * SCALE;
  }
  Wcat[idx] = v;
}

// bcat[576]; be folded into k- and v-bias so e's bias is handled exactly
__global__ void k_prep_b(const float* __restrict__ bq, const float* __restrict__ bk,
                         const float* __restrict__ bv, const float* __restrict__ br,
                         const float* __restrict__ be, const float* __restrict__ We,
                         float* __restrict__ bcat) {
  int j = blockIdx.x * 256 + threadIdx.x;
  if (j >= DCAT) return;
  float v;
  if (j < 128)       v = bq[j] * SCALE;
  else if (j < 384) {
    int t = j - 128, g = t >> 2, r = t & 3;
    int col = 2*g + (r & 1);
    v = ((r < 2) ? bk[col] : bv[col]) + be[col];
  }
  else if (j < 512)  v = br[j-384];
  else {
    int c = j - 512;
    float a = 0.f;
    for (int t = 0; t < DEMB; ++t) a += bq[t] * We[c*DEMB + t];
    v = a * SCALE;
  }
  bcat[j] = v;
}

// ---------- CSR build ----------
__global__ void k_deg(const int* __restrict__ ei, int* __restrict__ degi, int nE) {
  int e = blockIdx.x * 256 + threadIdx.x;
  if (e < nE) atomicAdd(&degi[ei[nE + e]], 1);
}

__global__ void k_dinv(const int* __restrict__ degi, float* __restrict__ dinv, int nN) {
  int n = blockIdx.x * 256 + threadIdx.x;
  if (n < nN) dinv[n] = rsqrtf(1.0f + (float)degi[n]);
}

__global__ __launch_bounds__(1024) void k_scan(const int* __restrict__ degi,
                                               int* __restrict__ row_ptr, int n) {
  __shared__ int sm[1024];
  __shared__ int carry;
  if (threadIdx.x == 0) carry = 0;
  __syncthreads();
  for (int base = 0; base < n; base += 1024) {
    int i = base + threadIdx.x;
    int v = (i < n) ? degi[i] : 0;
    sm[threadIdx.x] = v;
    __syncthreads();
    int val = v;
    for (int off = 1; off < 1024; off <<= 1) {
      int t = (threadIdx.x >= off) ? sm[threadIdx.x - off] : 0;
      __syncthreads();
      val += t;
      sm[threadIdx.x] = val;
      __syncthreads();
    }
    int c0 = carry;
    if (i < n) row_ptr[i] = c0 + val - v;   // exclusive
    int total = sm[1023];
    __syncthreads();
    if (threadIdx.x == 0) carry = c0 + total;
    __syncthreads();
  }
  if (threadIdx.x == 0) row_ptr[n] = carry;
}

__global__ void k_scatter(const int* __restrict__ ei, const int* __restrict__ row_ptr,
                          int* __restrict__ cursor, int2* __restrict__ csr_se, int nE) {
  int e = blockIdx.x * 256 + threadIdx.x;
  if (e >= nE) return;
  int dst = ei[nE + e];
  int pos = row_ptr[dst] + atomicAdd(&cursor[dst], 1);
  csr_se[pos] = make_int2(ei[e], e);
}

// ---------- generic f32 GEMM: C[M,Ncols] = (A[M,K] @ B[K,Ncols] + bias) * row_scale ----------
__global__ __launch_bounds__(256) void k_gemm(const float* __restrict__ A,
                                              const float* __restrict__ B,
                                              const float* __restrict__ bias,
                                              const float* __restrict__ row_scale,
                                              float* __restrict__ C,
                                              int M, int Ncols, int K) {
  __shared__ float As[16][128];
  __shared__ float Bs[16][64];
  int tid = threadIdx.x;
  int tx = tid & 15, ty = tid >> 4;
  int bm0 = blockIdx.x * 128;
  int bn0 = blockIdx.y * 64;
  float acc[8][4] = {};
  for (int k0 = 0; k0 < K; k0 += 16) {
    #pragma unroll
    for (int j = 0; j < 2; ++j) {
      int idx = tid + j * 256;
      int row = idx >> 2, kg = idx & 3;
      int grow = bm0 + row;
      float4 a4 = make_float4(0.f, 0.f, 0.f, 0.f);
      if (grow < M) a4 = *reinterpret_cast<const float4*>(&A[(size_t)grow * K + k0 + kg * 4]);
      As[kg*4+0][row] = a4.x; As[kg*4+1][row] = a4.y;
      As[kg*4+2][row] = a4.z; As[kg*4+3][row] = a4.w;
    }
    {
      int row = tid >> 4, cg = tid & 15;
      float4 b4 = *reinterpret_cast<const float4*>(&B[(size_t)(k0 + row) * Ncols + bn0 + cg * 4]);
      *reinterpret_cast<float4*>(&Bs[row][cg * 4]) = b4;
    }
    __syncthreads();
    #pragma unroll
    for (int kk = 0; kk < 16; ++kk) {
      float a[8], b[4];
      #pragma unroll
      for (int r = 0; r < 8; ++r) a[r] = As[kk][ty * 8 + r];
      #pragma unroll
      for (int c = 0; c < 4; ++c) b[c] = Bs[kk][tx * 4 + c];
      #pragma unroll
      for (int r = 0; r < 8; ++r)
        #pragma unroll
        for (int c = 0; c < 4; ++c) acc[r][c] += a[r] * b[c];
    }
    __syncthreads();
  }
  #pragma unroll
  for (int r = 0; r < 8; ++r) {
    int grow = bm0 + ty * 8 + r;
    if (grow >= M) continue;
    int gcol = bn0 + tx * 4;
    float sc = row_scale ? row_scale[grow] : 1.f;
    float4 o;
    o.x = (acc[r][0] + (bias ? bias[gcol + 0] : 0.f)) * sc;
    o.y = (acc[r][1] + (bias ? bias[gcol + 1] : 0.f)) * sc;
    o.z = (acc[r][2] + (bias ? bias[gcol + 2] : 0.f)) * sc;
    o.w = (acc[r][3] + (bias ? bias[gcol + 3] : 0.f)) * sc;
    *reinterpret_cast<float4*>(&C[(size_t)grow * Ncols + gcol]) = o;
  }
}

// ---------- GCN aggregate: xws rows are pre-scaled by dinv[src]; pure gather-accumulate ----------
__global__ __launch_bounds__(256) void k_gcn(const float* __restrict__ xws,
                                             const int* __restrict__ row_ptr,
                                             const int2* __restrict__ csr_se,
                                             const float* __restrict__ dinv,
                                             const float* __restrict__ b1,
                                             float* __restrict__ h, int nN) {
  int wave = threadIdx.x >> 6, lane = threadIdx.x & 63;
  int n = blockIdx.x * 4 + wave;
  if (n >= nN) return;
  int beg = row_ptr[n], end = row_ptr[n + 1];
  float4 acc = make_float4(0.f, 0.f, 0.f, 0.f);
  int i = beg;
  for (; i + CK <= end; i += CK) {
    int srcs[CK];
    #pragma unroll
    for (int j = 0; j < CK; ++j) srcs[j] = csr_se[i + j].x;
    float4 xv[CK];
    #pragma unroll
    for (int j = 0; j < CK; ++j)
      xv[j] = *reinterpret_cast<const float4*>(&xws[(size_t)srcs[j] * DHID + lane * 4]);
    #pragma unroll
    for (int j = 0; j < CK; ++j) {
      acc.x += xv[j].x; acc.y += xv[j].y; acc.z += xv[j].z; acc.w += xv[j].w;
    }
  }
  for (; i < end; ++i) {
    int src = csr_se[i].x;
    float4 xv = *reinterpret_cast<const float4*>(&xws[(size_t)src * DHID + lane * 4]);
    acc.x += xv.x; acc.y += xv.y; acc.z += xv.z; acc.w += xv.w;
  }
  float dn = dinv[n];
  float4 xs = *reinterpret_cast<const float4*>(&xws[(size_t)n * DHID + lane * 4]);
  float4 bb = *reinterpret_cast<const float4*>(&b1[lane * 4]);
  float4 o;
  o.x = fmaxf((acc.x + xs.x) * dn + bb.x, 0.f);
  o.y = fmaxf((acc.y + xs.y) * dn + bb.y, 0.f);
  o.z = fmaxf((acc.z + xs.z) * dn + bb.z, 0.f);
  o.w = fmaxf((acc.w + xs.w) * dn + bb.w, 0.f);
  *reinterpret_cast<float4*>(&h[(size_t)n * DHID + lane * 4]) = o;
}

// ---------- fused attention + root + LayerNorm + pool: one wave per dst node, 8-edge chunks ----------
__global__ __launch_bounds__(256) void k_attn(const float* __restrict__ qkvr,
                                              const float* __restrict__ edge_attr,
                                              const float* __restrict__ We,
                                              const int* __restrict__ row_ptr,
                                              const int2* __restrict__ csr_se,
                                              const int* __restrict__ batch,
                                              const float* __restrict__ gamma,
                                              const float* __restrict__ beta,
                                              float* __restrict__ pool,
                                              float* __restrict__ cnt, int nN) {
  int wave = threadIdx.x >> 6, lane = threadIdx.x & 63;
  int n = blockIdx.x * 4 + wave;
  if (n >= nN) return;
  const float* base = &qkvr[(size_t)n * DCAT];
  float2 q2 = *reinterpret_cast<const float2*>(&base[lane * 2]);   // pre-scaled by 1/sqrt(128)
  float wqe = base[EOFF + lane];                                   // (We@q)*s
  float m = -1e30f, s = 0.f, eacc = 0.f;
  float2 vacc = make_float2(0.f, 0.f);
  int beg = row_ptr[n], end = row_ptr[n + 1];
  int i = beg;
  for (; i + CK <= end; i += CK) {
    int2 se[CK];
    #pragma unroll
    for (int j = 0; j < CK; ++j) se[j] = csr_se[i + j];
    float4 kv[CK]; float ea[CK];
    #pragma unroll
    for (int j = 0; j < CK; ++j) {
      kv[j] = *reinterpret_cast<const float4*>(&qkvr[(size_t)se[j].x * DCAT + KOFF + lane * 4]);
      ea[j] = edge_attr[(size_t)se[j].y * DE + lane];
    }
    float part[CK];
    #pragma unroll
    for (int j = 0; j < CK; ++j)
      part[j] = ea[j] * wqe + kv[j].x * q2.x + kv[j].y * q2.y;
    #pragma unroll
    for (int off = 1; off < 64; off <<= 1) {
      #pragma unroll
      for (int j = 0; j < CK; ++j) part[j] += __shfl_xor(part[j], off);
    }
    float cmax = part[0];
    #pragma unroll
    for (int j = 1; j < CK; ++j) cmax = fmaxf(cmax, part[j]);
    float p[CK];
    #pragma unroll
    for (int j = 0; j < CK; ++j) p[j] = __expf(part[j] - cmax);
    float csum = 0.f, ce = 0.f;
    float2 cv = make_float2(0.f, 0.f);
    #pragma unroll
    for (int j = 0; j < CK; ++j) {
      csum += p[j];
      cv.x += p[j] * kv[j].z; cv.y += p[j] * kv[j].w;
      ce += p[j] * ea[j];
    }
    float mn = fmaxf(m, cmax);
    float cs = __expf(m - mn), cp = __expf(cmax - mn);
    s = s * cs + csum * cp;
    vacc.x = vacc.x * cs + cv.x * cp;
    vacc.y = vacc.y * cs + cv.y * cp;
    eacc = eacc * cs + ce * cp;
    m = mn;
  }
  for (; i < end; ++i) {                       // tail (<CK edges)
    int2 se = csr_se[i];
    float4 kv = *reinterpret_cast<const float4*>(&qkvr[(size_t)se.x * DCAT + KOFF + lane * 4]);
    float ea1 = edge_attr[(size_t)se.y * DE + lane];
    float part = ea1 * wqe + kv.x * q2.x + kv.y * q2.y;
    #pragma unroll
    for (int off = 1; off < 64; off <<= 1) part += __shfl_xor(part, off);
    float mn = fmaxf(m, part);
    float cs = __expf(m - mn), p = __expf(part - mn);
    s = s * cs + p;
    vacc.x = vacc.x * cs + p * kv.z;
    vacc.y = vacc.y * cs + p * kv.w;
    eacc = eacc * cs + p * ea1;
    m = mn;
  }
  float2 o2 = make_float2(0.f, 0.f);
  if (s > 0.f) {
    float inv = 1.f / s;
    vacc.x *= inv; vacc.y *= inv; eacc *= inv;
    o2 = vacc;
    // out += (sum alpha*edge_attr) @ We  — per-node 64x128 matvec via readlane broadcast
    #pragma unroll 8
    for (int c = 0; c < 64; ++c) {
      float ec = __shfl(eacc, c);
      float2 w2 = *reinterpret_cast<const float2*>(&We[c * DEMB + lane * 2]);
      o2.x += ec * w2.x; o2.y += ec * w2.y;
    }
  }
  float2 hr2 = *reinterpret_cast<const float2*>(&base[ROFF + lane * 2]);
  o2.x += hr2.x; o2.y += hr2.y;
  // LayerNorm over 128 (biased var) + ReLU
  float s1 = o2.x + o2.y, sq = o2.x * o2.x + o2.y * o2.y;
  #pragma unroll
  for (int off = 1; off < 64; off <<= 1) {
    s1 += __shfl_xor(s1, off);
    sq += __shfl_xor(sq, off);
  }
  float mu = s1 * (1.f / 128.f);
  float var = sq * (1.f / 128.f) - mu * mu;
  float rstd = rsqrtf(var + 1e-5f);
  float2 g2 = *reinterpret_cast<const float2*>(&gamma[lane * 2]);
  float2 b2 = *reinterpret_cast<const float2*>(&beta[lane * 2]);
  float y0 = fmaxf((o2.x - mu) * rstd * g2.x + b2.x, 0.f);
  float y1 = fmaxf((o2.y - mu) * rstd * g2.y + b2.y, 0.f);
  int b = batch[n];
  atomicAdd(&pool[b * DEMB + lane * 2 + 0], y0);
  atomicAdd(&pool[b * DEMB + lane * 2 + 1], y1);
  if (lane == 0) atomicAdd(&cnt[b], 1.f);
}

__global__ void k_final(const float* __restrict__ pool, const float* __restrict__ cnt,
                        float* __restrict__ out, int total) {
  int i = blockIdx.x * 256 + threadIdx.x;
  if (i < total) out[i] = pool[i] / fmaxf(cnt[i >> 7], 1.f);
}

extern "C" void kernel_launch(void* const* d_in, const int* in_sizes, int n_in,
                              void* d_out, int out_size, void* d_ws, size_t ws_size,
                              hipStream_t stream) {
  const float* x         = (const float*)d_in[0];
  const float* edge_attr = (const float*)d_in[1];
  const int*   edge_index= (const int*)d_in[2];
  const int*   batch     = (const int*)d_in[3];
  const float* W1 = (const float*)d_in[4];
  const float* b1 = (const float*)d_in[5];
  const float* Wq = (const float*)d_in[6];  const float* bq = (const float*)d_in[7];
  const float* Wk = (const float*)d_in[8];  const float* bk = (const float*)d_in[9];
  const float* Wv = (const float*)d_in[10]; const float* bv = (const float*)d_in[11];
  const float* We = (const float*)d_in[12]; const float* be = (const float*)d_in[13];
  const float* Wr = (const float*)d_in[14]; const float* br = (const float*)d_in[15];
  const float* gamma = (const float*)d_in[16];
  const float* beta  = (const float*)d_in[17];
  float* out = (float*)d_out;

  const int nN = in_sizes[0] / DN;       // 50000
  const int nE = in_sizes[1] / DE;       // 1600000

  // ---- workspace layout (bump allocator, 256B aligned) ----
  char* p = (char*)d_ws;
  auto alloc = [&](size_t bytes) -> void* {
    void* r = (void*)p;
    p += (bytes + 255) & ~(size_t)255;
    return r;
  };
  // zeroed region first (one memset)
  int*   degi   = (int*)  alloc((size_t)nN * 4);
  int*   cursor = (int*)  alloc((size_t)nN * 4);
  float* pool   = (float*)alloc((size_t)out_size * 4);
  float* cnt    = (float*)alloc(64 * 4);
  size_t zero_bytes = (size_t)(p - (char*)d_ws);
  int*   row_ptr = (int*)  alloc((size_t)(nN + 1) * 4);
  float* dinv    = (float*)alloc((size_t)nN * 4);
  int2*  csr_se  = (int2*) alloc((size_t)nE * 8);
  float* Wcat    = (float*)alloc((size_t)DHID * DCAT * 4);
  float* bcat    = (float*)alloc((size_t)DCAT * 4);
  float* h       = (float*)alloc((size_t)nN * DHID * 4);
  // xws is dead after k_gcn; alias it with qkvr's region (qkvr is larger)
  float* qkvr    = (float*)alloc((size_t)nN * DCAT * 4);
  float* xws     = qkvr;
  size_t required = (size_t)(p - (char*)d_ws);
  if (ws_size < required) return;  // refuse to scribble past the workspace

  hipMemsetAsync(d_ws, 0, zero_bytes, stream);

  k_prep_w<<<(DHID * DCAT + 255) / 256, 256, 0, stream>>>(Wq, Wk, Wv, Wr, We, Wcat);
  k_prep_b<<<3, 256, 0, stream>>>(bq, bk, bv, br, be, We, bcat);
  k_deg<<<(nE + 255) / 256, 256, 0, stream>>>(edge_index, degi, nE);
  k_dinv<<<(nN + 255) / 256, 256, 0, stream>>>(degi, dinv, nN);
  k_scan<<<1, 1024, 0, stream>>>(degi, row_ptr, nN);
  k_scatter<<<(nE + 255) / 256, 256, 0, stream>>>(edge_index, row_ptr, cursor,
                                                  csr_se, nE);
  // xws = (x @ W1) * dinv[row]   [nN,128]@[128,256]
  {
    dim3 g((nN + 127) / 128, DHID / 64);
    k_gemm<<<g, 256, 0, stream>>>(x, W1, nullptr, dinv, xws, nN, DHID, DN);
  }
  k_gcn<<<(nN + 3) / 4, 256, 0, stream>>>(xws, row_ptr, csr_se, dinv, b1, h, nN);
  // qkvr = h @ Wcat + bcat   [nN,256]@[256,576]  (overwrites xws region — xws is dead)
  {
    dim3 g((nN + 127) / 128, DCAT / 64);
    k_gemm<<<g, 256, 0, stream>>>(h, Wcat, bcat, nullptr, qkvr, nN, DCAT, DHID);
  }
  k_attn<<<(nN + 3) / 4, 256, 0, stream>>>(qkvr, edge_attr, We, row_ptr, csr_se,
                                           batch, gamma, beta, pool, cnt, nN);
  k_final<<<(out_size + 255) / 256, 256, 0, stream>>>(pool, cnt, out, out_size);
}

// Round 5
// 1241.102 us; speedup vs baseline: 1.0560x; 1.0378x over previous
//
#include <hip/hip_runtime.h>

typedef short bf16x8 __attribute__((ext_vector_type(8)));
typedef float f32x4 __attribute__((ext_vector_type(4)));

#define DN 128
#define DE 64
#define DEMB 128
#define DHID 256
#define SCALE 0.08838834764831845f  // 1/sqrt(128)

__device__ __forceinline__ ushort f2bf(float f) {
  unsigned u = __float_as_uint(f);
  return (ushort)((u + 0x7FFFu + ((u >> 16) & 1u)) >> 16);  // RNE
}

// ---------- weight pack for GEMM1: W1[128][256] -> frag order, bf16 ----------
// Wp1[((t*4+s)*64+lane)*8+j] = bf16( W1[s*32+(lane>>4)*8+j][t*16+(lane&15)] )
__global__ void k_prep1(const float* __restrict__ W1, ushort* __restrict__ Wp1) {
  int idx = blockIdx.x * 256 + threadIdx.x;
  if (idx >= 16 * 4 * 64 * 8) return;
  int j = idx & 7, lane = (idx >> 3) & 63, s = (idx >> 9) & 3, t = idx >> 11;
  int k = s * 32 + (lane >> 4) * 8 + j;
  int c = t * 16 + (lane & 15);
  Wp1[idx] = f2bf(W1[k * DHID + c]);
}

// ---------- weight pack for GEMM2: virtual Wcat[256][576] -> frag order, bf16 ----------
// col map: [0,128)=Wq*s | [128,384)=kv blocks of 8 (k[4g..+3],v[4g..+3]) | [384,512)=Wr | [512,576)=(Wq@We^T)*s
__global__ void k_prep2(const float* __restrict__ Wq, const float* __restrict__ Wk,
                        const float* __restrict__ Wv, const float* __restrict__ Wr,
                        const float* __restrict__ We, ushort* __restrict__ Wp2) {
  int idx = blockIdx.x * 256 + threadIdx.x;
  if (idx >= 36 * 8 * 64 * 8) return;
  int j = idx & 7, lane = (idx >> 3) & 63, s = (idx >> 9) & 7, t = idx >> 12;
  int k = s * 32 + (lane >> 4) * 8 + j;
  int c = t * 16 + (lane & 15);
  float v;
  if (c < 128)       v = Wq[k * DEMB + c] * SCALE;
  else if (c < 384) {
    int tt = c - 128, g = tt >> 3, r = tt & 7, col = 4 * g + (r & 3);
    v = (r < 4) ? Wk[k * DEMB + col] : Wv[k * DEMB + col];
  }
  else if (c < 512)  v = Wr[k * DEMB + (c - 384)];
  else {
    int cc = c - 512;
    float a = 0.f;
    for (int u = 0; u < DEMB; ++u) a += Wq[k * DEMB + u] * We[cc * DEMB + u];
    v = a * SCALE;
  }
  Wp2[idx] = f2bf(v);
}

// bcat[576] f32; be folded into k/v bias
__global__ void k_prep_b(const float* __restrict__ bq, const float* __restrict__ bk,
                         const float* __restrict__ bv, const float* __restrict__ br,
                         const float* __restrict__ be, const float* __restrict__ We,
                         float* __restrict__ bcat) {
  int j = blockIdx.x * 256 + threadIdx.x;
  if (j >= 576) return;
  float v;
  if (j < 128)       v = bq[j] * SCALE;
  else if (j < 384) {
    int tt = j - 128, g = tt >> 3, r = tt & 7, col = 4 * g + (r & 3);
    v = ((r < 4) ? bk[col] : bv[col]) + be[col];
  }
  else if (j < 512)  v = br[j - 384];
  else {
    int cc = j - 512;
    float a = 0.f;
    for (int u = 0; u < DEMB; ++u) a += bq[u] * We[cc * DEMB + u];
    v = a * SCALE;
  }
  bcat[j] = v;
}

// ---------- CSR build ----------
__global__ void k_deg(const int* __restrict__ ei, int* __restrict__ degi, int nE) {
  int e = blockIdx.x * 256 + threadIdx.x;
  if (e < nE) atomicAdd(&degi[ei[nE + e]], 1);
}

__global__ void k_dinv(const int* __restrict__ degi, float* __restrict__ dinv, int nN) {
  int n = blockIdx.x * 256 + threadIdx.x;
  if (n < nN) dinv[n] = rsqrtf(1.0f + (float)degi[n]);
}

__global__ __launch_bounds__(1024) void k_scan(const int* __restrict__ degi,
                                               int* __restrict__ row_ptr, int n) {
  __shared__ int sm[1024];
  __shared__ int carry;
  if (threadIdx.x == 0) carry = 0;
  __syncthreads();
  for (int base = 0; base < n; base += 1024) {
    int i = base + threadIdx.x;
    int v = (i < n) ? degi[i] : 0;
    sm[threadIdx.x] = v;
    __syncthreads();
    int val = v;
    for (int off = 1; off < 1024; off <<= 1) {
      int t = (threadIdx.x >= off) ? sm[threadIdx.x - off] : 0;
      __syncthreads();
      val += t;
      sm[threadIdx.x] = val;
      __syncthreads();
    }
    int c0 = carry;
    if (i < n) row_ptr[i] = c0 + val - v;
    int total = sm[1023];
    __syncthreads();
    if (threadIdx.x == 0) carry = c0 + total;
    __syncthreads();
  }
  if (threadIdx.x == 0) row_ptr[n] = carry;
}

__global__ void k_scatter(const int* __restrict__ ei, const int* __restrict__ row_ptr,
                          int* __restrict__ cursor, int2* __restrict__ csr_se, int nE) {
  int e = blockIdx.x * 256 + threadIdx.x;
  if (e >= nE) return;
  int dst = ei[nE + e];
  int pos = row_ptr[dst] + atomicAdd(&cursor[dst], 1);
  csr_se[pos] = make_int2(ei[e], e);
}

// ---------- GEMM1 (MFMA bf16): xwsb[n][256] = bf16( (x @ W1) * dinv[n] ) ----------
// block = 256 thr = 4 waves; block covers 16 rows; wave w owns n-tiles w*4..w*4+3
__global__ __launch_bounds__(256) void k_gemm1(const float* __restrict__ x,
                                               const ushort* __restrict__ Wp1,
                                               const float* __restrict__ dinv,
                                               ushort* __restrict__ xwsb, int nN) {
  int lane = threadIdx.x & 63, wave = threadIdx.x >> 6;
  int l15 = lane & 15, lh = lane >> 4;
  int m0 = blockIdx.x * 16;
  int rowa = m0 + l15; if (rowa >= nN) rowa = nN - 1;
  f32x4 acc[4] = {};
  for (int s = 0; s < 4; ++s) {
    const float* ap = &x[(size_t)rowa * DN + s * 32 + lh * 8];
    float4 a0 = *(const float4*)ap;
    float4 a1 = *(const float4*)(ap + 4);
    bf16x8 af;
    af[0] = (short)f2bf(a0.x); af[1] = (short)f2bf(a0.y);
    af[2] = (short)f2bf(a0.z); af[3] = (short)f2bf(a0.w);
    af[4] = (short)f2bf(a1.x); af[5] = (short)f2bf(a1.y);
    af[6] = (short)f2bf(a1.z); af[7] = (short)f2bf(a1.w);
    #pragma unroll
    for (int tt = 0; tt < 4; ++tt) {
      int t = wave * 4 + tt;
      bf16x8 bf = *(const bf16x8*)&Wp1[((t * 4 + s) * 64 + lane) * 8];
      acc[tt] = __builtin_amdgcn_mfma_f32_16x16x32_bf16(af, bf, acc[tt], 0, 0, 0);
    }
  }
  #pragma unroll
  for (int tt = 0; tt < 4; ++tt) {
    int c = (wave * 4 + tt) * 16 + l15;
    #pragma unroll
    for (int r = 0; r < 4; ++r) {
      int row = m0 + lh * 4 + r;
      if (row < nN) xwsb[(size_t)row * DHID + c] = f2bf(acc[tt][r] * dinv[row]);
    }
  }
}

// ---------- GEMM2 (MFMA bf16): [q f32 | kv bf16 | hr f32 | wqe f32] from hb @ Wp2 ----------
// block = 256 thr = 4 waves; 16 rows; wave w owns n-tiles w*9..w*9+8 (36 tiles = 576 cols)
__global__ __launch_bounds__(256) void k_gemm2(const ushort* __restrict__ hb,
                                               const ushort* __restrict__ Wp2,
                                               const float* __restrict__ bcat,
                                               float* __restrict__ qr,
                                               ushort* __restrict__ kvb, int nN) {
  int lane = threadIdx.x & 63, wave = threadIdx.x >> 6;
  int l15 = lane & 15, lh = lane >> 4;
  int m0 = blockIdx.x * 16;
  int rowa = m0 + l15; if (rowa >= nN) rowa = nN - 1;
  f32x4 acc[9] = {};
  for (int s = 0; s < 8; ++s) {
    bf16x8 af = *(const bf16x8*)&hb[(size_t)rowa * DHID + s * 32 + lh * 8];
    #pragma unroll
    for (int tt = 0; tt < 9; ++tt) {
      int t = wave * 9 + tt;
      bf16x8 bf = *(const bf16x8*)&Wp2[((t * 8 + s) * 64 + lane) * 8];
      acc[tt] = __builtin_amdgcn_mfma_f32_16x16x32_bf16(af, bf, acc[tt], 0, 0, 0);
    }
  }
  #pragma unroll
  for (int tt = 0; tt < 9; ++tt) {
    int c = (wave * 9 + tt) * 16 + l15;
    float bc = bcat[c];
    #pragma unroll
    for (int r = 0; r < 4; ++r) {
      int row = m0 + lh * 4 + r;
      if (row >= nN) continue;
      float val = acc[tt][r] + bc;
      if (c < 128)      qr[(size_t)row * 320 + c] = val;
      else if (c < 384) kvb[(size_t)row * 256 + (c - 128)] = f2bf(val);
      else if (c < 512) qr[(size_t)row * 320 + 128 + (c - 384)] = val;
      else              qr[(size_t)row * 320 + 256 + (c - 512)] = val;
    }
  }
}

// ---------- GCN aggregate: 2 edges/instr (32-lane groups), bf16 gathers ----------
#define GC 8
__global__ __launch_bounds__(256) void k_gcn(const ushort* __restrict__ xwsb,
                                             const int* __restrict__ row_ptr,
                                             const int2* __restrict__ csr_se,
                                             const float* __restrict__ dinv,
                                             const float* __restrict__ b1,
                                             ushort* __restrict__ hb, int nN) {
  int lane = threadIdx.x & 63;
  int n = blockIdx.x * 4 + (threadIdx.x >> 6);
  if (n >= nN) return;
  int grp = lane >> 5, l5 = lane & 31;
  int beg = row_ptr[n], end = row_ptr[n + 1];
  float acc[8] = {};
  for (int i = beg; i < end; i += 2 * GC) {
    int src[GC]; float w[GC];
    #pragma unroll
    for (int j = 0; j < GC; ++j) {
      int e = i + 2 * j + grp;
      int cl = e < end ? e : end - 1;
      src[j] = csr_se[cl].x;
      w[j] = e < end ? 1.f : 0.f;
    }
    uint4 kv[GC];
    #pragma unroll
    for (int j = 0; j < GC; ++j)
      kv[j] = *(const uint4*)&xwsb[(size_t)src[j] * DHID + l5 * 8];
    #pragma unroll
    for (int j = 0; j < GC; ++j) {
      unsigned q[4] = {kv[j].x, kv[j].y, kv[j].z, kv[j].w};
      #pragma unroll
      for (int d = 0; d < 4; ++d) {
        acc[2*d]   = fmaf(w[j], __uint_as_float(q[d] << 16), acc[2*d]);
        acc[2*d+1] = fmaf(w[j], __uint_as_float(q[d] & 0xFFFF0000u), acc[2*d+1]);
      }
    }
  }
  #pragma unroll
  for (int d = 0; d < 8; ++d) acc[d] += __shfl_xor(acc[d], 32);
  uint4 sv = *(const uint4*)&xwsb[(size_t)n * DHID + l5 * 8];
  unsigned sq[4] = {sv.x, sv.y, sv.z, sv.w};
  float dn = dinv[n];
  float4 bb0 = *(const float4*)&b1[l5 * 8];
  float4 bb1 = *(const float4*)&b1[l5 * 8 + 4];
  float bbs[8] = {bb0.x, bb0.y, bb0.z, bb0.w, bb1.x, bb1.y, bb1.z, bb1.w};
  unsigned ov[4];
  #pragma unroll
  for (int d = 0; d < 4; ++d) {
    float lo = __uint_as_float(sq[d] << 16);
    float hi = __uint_as_float(sq[d] & 0xFFFF0000u);
    float v0 = fmaxf((acc[2*d]   + lo) * dn + bbs[2*d],   0.f);
    float v1 = fmaxf((acc[2*d+1] + hi) * dn + bbs[2*d+1], 0.f);
    ov[d] = (unsigned)f2bf(v0) | ((unsigned)f2bf(v1) << 16);
  }
  if (grp == 0) {
    uint4 o = {ov[0], ov[1], ov[2], ov[3]};
    *(uint4*)&hb[(size_t)n * DHID + l5 * 8] = o;
  }
}

// ---------- fused attention + root + LN + pool: 2 edges/instr, no-max softmax ----------
#define AC 8
__global__ __launch_bounds__(256) void k_attn(const float* __restrict__ qr,
                                              const ushort* __restrict__ kvb,
                                              const float* __restrict__ edge_attr,
                                              const float* __restrict__ We,
                                              const int* __restrict__ row_ptr,
                                              const int2* __restrict__ csr_se,
                                              const int* __restrict__ batch,
                                              const float* __restrict__ gamma,
                                              const float* __restrict__ beta,
                                              float* __restrict__ pool,
                                              float* __restrict__ cnt, int nN) {
  int lane = threadIdx.x & 63;
  int n = blockIdx.x * 4 + (threadIdx.x >> 6);
  if (n >= nN) return;
  int grp = lane >> 5, l5 = lane & 31;
  const float* qb = &qr[(size_t)n * 320];
  float4 q4  = *(const float4*)&qb[l5 * 4];        // q dims 4*l5.., pre-scaled
  float2 we2 = *(const float2*)&qb[256 + l5 * 2];  // wqe dims 2*l5..
  float s = 0.f;
  float4 vacc = {0, 0, 0, 0};
  float2 eacc = {0, 0};
  int beg = row_ptr[n], end = row_ptr[n + 1];
  for (int i = beg; i < end; i += 2 * AC) {
    int2 se[AC]; float w[AC];
    #pragma unroll
    for (int j = 0; j < AC; ++j) {
      int e = i + 2 * j + grp;
      int cl = e < end ? e : end - 1;
      se[j] = csr_se[cl];
      w[j] = e < end ? 1.f : 0.f;
    }
    uint4 kv[AC]; float2 ea[AC];
    #pragma unroll
    for (int j = 0; j < AC; ++j) {
      kv[j] = *(const uint4*)&kvb[(size_t)se[j].x * DHID + l5 * 8];
      ea[j] = *(const float2*)&edge_attr[(size_t)se[j].y * DE + l5 * 2];
    }
    #pragma unroll
    for (int j = 0; j < AC; ++j) {
      float k0 = __uint_as_float(kv[j].x << 16);
      float k1 = __uint_as_float(kv[j].x & 0xFFFF0000u);
      float k2 = __uint_as_float(kv[j].y << 16);
      float k3 = __uint_as_float(kv[j].y & 0xFFFF0000u);
      float part = q4.x * k0 + q4.y * k1 + q4.z * k2 + q4.w * k3
                 + we2.x * ea[j].x + we2.y * ea[j].y;
      #pragma unroll
      for (int off = 1; off < 32; off <<= 1) part += __shfl_xor(part, off);
      float p = w[j] * __expf(part);               // softmax shift-invariance: no max needed
      s += p;
      vacc.x += p * __uint_as_float(kv[j].z << 16);
      vacc.y += p * __uint_as_float(kv[j].z & 0xFFFF0000u);
      vacc.z += p * __uint_as_float(kv[j].w << 16);
      vacc.w += p * __uint_as_float(kv[j].w & 0xFFFF0000u);
      eacc.x += p * ea[j].x;
      eacc.y += p * ea[j].y;
    }
  }
  s      += __shfl_xor(s, 32);
  vacc.x += __shfl_xor(vacc.x, 32); vacc.y += __shfl_xor(vacc.y, 32);
  vacc.z += __shfl_xor(vacc.z, 32); vacc.w += __shfl_xor(vacc.w, 32);
  eacc.x += __shfl_xor(eacc.x, 32); eacc.y += __shfl_xor(eacc.y, 32);
  float4 o4 = {0, 0, 0, 0};
  if (s > 0.f) {
    float inv = 1.f / s;
    o4.x = vacc.x * inv; o4.y = vacc.y * inv;
    o4.z = vacc.z * inv; o4.w = vacc.w * inv;
    float ex = eacc.x * inv, ey = eacc.y * inv;
    #pragma unroll 8
    for (int c = 0; c < 64; c += 2) {
      float e0 = __shfl(ex, c >> 1);
      float e1 = __shfl(ey, c >> 1);
      float4 w0 = *(const float4*)&We[c * DEMB + l5 * 4];
      float4 w1 = *(const float4*)&We[(c + 1) * DEMB + l5 * 4];
      o4.x += e0 * w0.x + e1 * w1.x;
      o4.y += e0 * w0.y + e1 * w1.y;
      o4.z += e0 * w0.z + e1 * w1.z;
      o4.w += e0 * w0.w + e1 * w1.w;
    }
  }
  float4 hr = *(const float4*)&qb[128 + l5 * 4];
  o4.x += hr.x; o4.y += hr.y; o4.z += hr.z; o4.w += hr.w;
  float s1 = o4.x + o4.y + o4.z + o4.w;
  float sq = o4.x*o4.x + o4.y*o4.y + o4.z*o4.z + o4.w*o4.w;
  #pragma unroll
  for (int off = 1; off < 32; off <<= 1) {
    s1 += __shfl_xor(s1, off);
    sq += __shfl_xor(sq, off);
  }
  float mu = s1 * (1.f / 128.f);
  float var = sq * (1.f / 128.f) - mu * mu;
  float rstd = rsqrtf(var + 1e-5f);
  float4 g4 = *(const float4*)&gamma[l5 * 4];
  float4 b4 = *(const float4*)&beta[l5 * 4];
  if (grp == 0) {
    int b = batch[n];
    atomicAdd(&pool[b * DEMB + l5 * 4 + 0], fmaxf((o4.x - mu) * rstd * g4.x + b4.x, 0.f));
    atomicAdd(&pool[b * DEMB + l5 * 4 + 1], fmaxf((o4.y - mu) * rstd * g4.y + b4.y, 0.f));
    atomicAdd(&pool[b * DEMB + l5 * 4 + 2], fmaxf((o4.z - mu) * rstd * g4.z + b4.z, 0.f));
    atomicAdd(&pool[b * DEMB + l5 * 4 + 3], fmaxf((o4.w - mu) * rstd * g4.w + b4.w, 0.f));
    if (l5 == 0) atomicAdd(&cnt[b], 1.f);
  }
}

__global__ void k_final(const float* __restrict__ pool, const float* __restrict__ cnt,
                        float* __restrict__ out, int total) {
  int i = blockIdx.x * 256 + threadIdx.x;
  if (i < total) out[i] = pool[i] / fmaxf(cnt[i >> 7], 1.f);
}

extern "C" void kernel_launch(void* const* d_in, const int* in_sizes, int n_in,
                              void* d_out, int out_size, void* d_ws, size_t ws_size,
                              hipStream_t stream) {
  const float* x         = (const float*)d_in[0];
  const float* edge_attr = (const float*)d_in[1];
  const int*   edge_index= (const int*)d_in[2];
  const int*   batch     = (const int*)d_in[3];
  const float* W1 = (const float*)d_in[4];
  const float* b1 = (const float*)d_in[5];
  const float* Wq = (const float*)d_in[6];  const float* bq = (const float*)d_in[7];
  const float* Wk = (const float*)d_in[8];  const float* bk = (const float*)d_in[9];
  const float* Wv = (const float*)d_in[10]; const float* bv = (const float*)d_in[11];
  const float* We = (const float*)d_in[12]; const float* be = (const float*)d_in[13];
  const float* Wr = (const float*)d_in[14]; const float* br = (const float*)d_in[15];
  const float* gamma = (const float*)d_in[16];
  const float* beta  = (const float*)d_in[17];
  float* out = (float*)d_out;

  const int nN = in_sizes[0] / DN;       // 50000
  const int nE = in_sizes[1] / DE;       // 1600000

  char* p = (char*)d_ws;
  auto alloc = [&](size_t bytes) -> void* {
    void* r = (void*)p;
    p += (bytes + 255) & ~(size_t)255;
    return r;
  };
  // zeroed region first
  int*   degi   = (int*)  alloc((size_t)nN * 4);
  int*   cursor = (int*)  alloc((size_t)nN * 4);
  float* pool   = (float*)alloc((size_t)out_size * 4);
  float* cnt    = (float*)alloc(64 * 4);
  size_t zero_bytes = (size_t)(p - (char*)d_ws);
  int*    row_ptr = (int*)   alloc((size_t)(nN + 1) * 4);
  float*  dinv    = (float*) alloc((size_t)nN * 4);
  int2*   csr_se  = (int2*)  alloc((size_t)nE * 8);
  ushort* Wp1     = (ushort*)alloc((size_t)16 * 4 * 64 * 8 * 2);
  ushort* Wp2     = (ushort*)alloc((size_t)36 * 8 * 64 * 8 * 2);
  float*  bcat    = (float*) alloc(576 * 4);
  float*  qr      = (float*) alloc((size_t)nN * 320 * 4);   // q|hr|wqe f32
  ushort* hb      = (ushort*)alloc((size_t)nN * DHID * 2);  // h bf16
  ushort* xwsb    = (ushort*)alloc((size_t)nN * DHID * 2);  // aliased: xws then kv
  ushort* kvb     = xwsb;   // xws dead after k_gcn; GEMM2 overwrites as kv table
  size_t required = (size_t)(p - (char*)d_ws);
  if (ws_size < required) return;

  hipMemsetAsync(d_ws, 0, zero_bytes, stream);

  k_prep1<<<128, 256, 0, stream>>>(W1, Wp1);
  k_prep2<<<576, 256, 0, stream>>>(Wq, Wk, Wv, Wr, We, Wp2);
  k_prep_b<<<3, 256, 0, stream>>>(bq, bk, bv, br, be, We, bcat);
  k_deg<<<(nE + 255) / 256, 256, 0, stream>>>(edge_index, degi, nE);
  k_dinv<<<(nN + 255) / 256, 256, 0, stream>>>(degi, dinv, nN);
  k_scan<<<1, 1024, 0, stream>>>(degi, row_ptr, nN);
  k_scatter<<<(nE + 255) / 256, 256, 0, stream>>>(edge_index, row_ptr, cursor, csr_se, nE);
  k_gemm1<<<(nN + 15) / 16, 256, 0, stream>>>(x, Wp1, dinv, xwsb, nN);
  k_gcn<<<(nN + 3) / 4, 256, 0, stream>>>(xwsb, row_ptr, csr_se, dinv, b1, hb, nN);
  k_gemm2<<<(nN + 15) / 16, 256, 0, stream>>>(hb, Wp2, bcat, qr, kvb, nN);
  k_attn<<<(nN + 3) / 4, 256, 0, stream>>>(qr, kvb, edge_attr, We, row_ptr, csr_se,
                                           batch, gamma, beta, pool, cnt, nN);
  k_final<<<(out_size + 255) / 256, 256, 0, stream>>>(pool, cnt, out, out_size);
}